// Round 10
// baseline (178.507 us; speedup 1.0000x reference)
//
#include <hip/hip_runtime.h>
#include <hip/hip_bf16.h>

// Problem constants
#define BATCH 8
#define TLEN 2048
#define CDIM 1024
#define HDIM 64
#define BT (BATCH * TLEN)   // 16384

typedef __attribute__((ext_vector_type(8))) short short8;
typedef __attribute__((ext_vector_type(4))) float f32x4;

#define GLOAD16(gsrc, lds) __builtin_amdgcn_global_load_lds( \
    (const __attribute__((address_space(1))) void*)(gsrc),   \
    (__attribute__((address_space(3))) void*)(lds), 16, 0, 0)

#if __has_builtin(__builtin_amdgcn_exp2f)
#define EXP2(x) __builtin_amdgcn_exp2f(x)
#else
#define EXP2(x) exp2f(x)
#endif

// round-to-nearest-even f32 -> bf16 (bit pattern)
__device__ inline unsigned bfbits(float f) {
    unsigned u = __builtin_bit_cast(unsigned, f);
    return (u + 0x7fffu + ((u >> 16) & 1u)) >> 16;
}
__device__ inline short bf1(float f) { return (short)bfbits(f); }
// packed f32x2 -> bf16x2 via HW instruction (src0 -> low half)
__device__ inline unsigned cvtpk(float lo, float hi) {
    unsigned r;
    asm("v_cvt_pk_bf16_f32 %0, %1, %2" : "=v"(r) : "v"(lo), "v"(hi));
    return r;
}

// ---------------------------------------------------------------------------
// Kernel 0: transpose + bf16-cast weights. Wt[3][64 n][1024 k] = W[k][n].
// Folds attention scale AND log2(e) into Wq (softmax runs in base 2).
// ---------------------------------------------------------------------------
__global__ __launch_bounds__(256) void wt_kernel(
        const float* __restrict__ Wq, const float* __restrict__ Wk,
        const float* __restrict__ Wv, short* __restrict__ Wt) {
    const int kc = blockIdx.x * 64;
    const int wi = blockIdx.y;
    const float* W = (wi == 0) ? Wq : ((wi == 1) ? Wk : Wv);
    const float scale = (wi == 0) ? 0.125f * 1.44269504088896f : 1.0f;
    __shared__ short tile[64][65];
    const int t = threadIdx.x;
    #pragma unroll
    for (int i = 0; i < 16; ++i) {
        int flat = i * 256 + t;
        int kk = flat >> 6, n = flat & 63;
        tile[kk][n] = bf1(W[(size_t)(kc + kk) * HDIM + n] * scale);
    }
    __syncthreads();
    const int n = t >> 2, c0 = (t & 3) * 16;
    #pragma unroll
    for (int i = 0; i < 16; ++i)
        Wt[((size_t)wi * 64 + n) * CDIM + kc + c0 + i] = tile[c0 + i][n];
}

// ---------------------------------------------------------------------------
// Kernel 1: QKV projection, 32 rows/block (512 blocks), 2-phase pipelined
// with COUNTED vmcnt (T4): stage(next) issued before the barrier stays in
// flight across it. Outputs: Q,K row-major [t][64]; V transposed Vt[b][h][t].
// ---------------------------------------------------------------------------
__global__ __launch_bounds__(256) void qkv_kernel(
        const float* __restrict__ x, const short* __restrict__ Wt,
        short* __restrict__ Q, short* __restrict__ K, short* __restrict__ Vt) {
    __shared__ float xs[2][32 * 64];      // 2 x 8 KB, swizzled
    __shared__ short wl[2][3 * 64 * 64];  // 2 x 24 KB, swizzled
    __shared__ short ob[32 * 72];         // epilogue staging (padded)
    const int t = threadIdx.x;
    const int lane = t & 63, w = t >> 6;
    const int lr = lane & 15, lg = lane >> 4;
    const int r0 = blockIdx.x * 32;

    auto stage = [&](int buf, int kc) {   // 8 global_load_lds per thread
        #pragma unroll
        for (int i = 0; i < 2; ++i) {
            int chunk = t + 256 * i;
            int row = chunk >> 4, slot = chunk & 15;
            GLOAD16(x + (size_t)(r0 + row) * CDIM + kc + ((slot ^ (row & 7)) << 2),
                    xs[buf] + chunk * 4);
        }
        #pragma unroll
        for (int i = 0; i < 6; ++i) {
            int chunk = t + 256 * i;
            int R = chunk >> 3, slot = chunk & 7;
            GLOAD16(Wt + (size_t)R * CDIM + kc + ((slot ^ (R & 7)) << 3),
                    wl[buf] + chunk * 8);
        }
    };

    f32x4 acc[3][2];
    #pragma unroll
    for (int wi = 0; wi < 3; ++wi)
        #pragma unroll
        for (int rt = 0; rt < 2; ++rt) acc[wi][rt] = f32x4{0.f, 0.f, 0.f, 0.f};

    stage(0, 0);
    int cur = 0;
    for (int kc = 0; kc < CDIM; kc += 64) {
        if (kc + 64 < CDIM) {
            stage(cur ^ 1, kc + 64);      // 8 new loads -> 16 outstanding
            asm volatile("s_waitcnt vmcnt(8)" ::: "memory");  // cur's 8 done
        } else {
            asm volatile("s_waitcnt vmcnt(0)" ::: "memory");  // drain last
        }
        __builtin_amdgcn_s_barrier();
        asm volatile("" ::: "memory");
        const float* xsc = xs[cur];
        const short* wlc = wl[cur];

        short8 af[2][2];
        #pragma unroll
        for (int rt = 0; rt < 2; ++rt)
            #pragma unroll
            for (int ks = 0; ks < 2; ++ks) {
                int row = rt * 16 + lr;
                int s0 = ks * 8 + lg * 2;
                f32x4 a0 = *(const f32x4*)(xsc + row * 64 + (((s0)     ^ (row & 7)) << 2));
                f32x4 a1 = *(const f32x4*)(xsc + row * 64 + (((s0 + 1) ^ (row & 7)) << 2));
                uint4 uu;
                uu.x = cvtpk(a0[0], a0[1]); uu.y = cvtpk(a0[2], a0[3]);
                uu.z = cvtpk(a1[0], a1[1]); uu.w = cvtpk(a1[2], a1[3]);
                af[rt][ks] = __builtin_bit_cast(short8, uu);
            }
        #pragma unroll
        for (int wi = 0; wi < 3; ++wi)
            #pragma unroll
            for (int ks = 0; ks < 2; ++ks) {
                int R = wi * 64 + w * 16 + lr;
                short8 bfv = *(const short8*)(wlc + R * 64 + (((ks * 4 + lg) ^ (lr & 7)) << 3));
                #pragma unroll
                for (int rt = 0; rt < 2; ++rt)
                    acc[wi][rt] = __builtin_amdgcn_mfma_f32_16x16x32_bf16(
                        af[rt][ks], bfv, acc[wi][rt], 0, 0, 0);
            }
        __builtin_amdgcn_s_barrier();
        cur ^= 1;
    }
    // V epilogue: C/D rows are consecutive t -> pack pairs, 8B stores to Vt[b][h][t]
    {
        const int bb = r0 >> 11, t0 = r0 & 2047;
        #pragma unroll
        for (int rt = 0; rt < 2; ++rt) {
            uint2 uv;
            uv.x = cvtpk(acc[2][rt][0], acc[2][rt][1]);
            uv.y = cvtpk(acc[2][rt][2], acc[2][rt][3]);
            *(uint2*)(Vt + ((size_t)bb * HDIM + w * 16 + lr) * TLEN + t0 + rt * 16 + lg * 4) = uv;
        }
    }
    // Q, K epilogue via LDS transpose -> coalesced short8 stores
    #pragma unroll
    for (int wi = 0; wi < 2; ++wi) {
        __syncthreads();
        #pragma unroll
        for (int rt = 0; rt < 2; ++rt)
            #pragma unroll
            for (int i = 0; i < 4; ++i)
                ob[(rt * 16 + lg * 4 + i) * 72 + w * 16 + lr] = bf1(acc[wi][rt][i]);
        __syncthreads();
        int row = t >> 3, c0 = (t & 7) * 8;
        short8 v = *(short8*)(ob + row * 72 + c0);
        short* dst = (wi == 0) ? Q : K;
        *(short8*)(dst + (size_t)(r0 + row) * HDIM + c0) = v;
    }
}

// ---------------------------------------------------------------------------
// Kernel 2: flash attention, causal, swapped QK^T, base-2 softmax.
// One 16-row q-tile per block (1024 blocks, 4/CU); 4 waves split kv 4-way,
// no barriers in the loop. V staged per-wave in LDS (coalesced gload_lds,
// swizzled source). K register-prefetch one supertile ahead via explicit
// two-phase ping-pong (named kfA/kfB) with sched_barrier(0) pins so the
// compiler cannot sink the prefetch to its use -- K L2 latency hides
// under the previous iteration's compute.
// ---------------------------------------------------------------------------
__global__ __launch_bounds__(256, 4) void attn_kernel(
        const short* __restrict__ Q, const short* __restrict__ K,
        const short* __restrict__ Vt, float* __restrict__ O) {
    __shared__ float arena[4][2048];   // 32 KB: per-wave V staging / merge Om+ml
    __shared__ short Ps[4][16 * 64];   // per-wave P buffer, XOR-swizzled (8 KB)
    const int t = threadIdx.x, lane = t & 63, w = t >> 6;
    const int lr = lane & 15, lg = lane >> 4;
    const int b = blockIdx.x;
    const int qi = (TLEN / 16 - 1) - blockIdx.y;   // descending: heavy first
    const int q0 = qi * 16;
    const size_t base = (size_t)b * TLEN * HDIM;
    const short* Kb = K + base;
    const short* Vb = Vt + base;    // same per-batch stride (64*2048)
    char* myPs = (char*)Ps[w];
    char* vbuf = (char*)arena[w];   // 8 KB per-wave V tile
    const int swz = (lr & 7) << 4;  // byte XOR within 128B row (P buffer)
    const int nsup = (q0 + 79) >> 6;
    const int r8 = lane >> 3, c8 = lane & 7;   // V staging coords

    auto stageV = [&](int s) {
        const int kv0 = s * 64;
        #pragma unroll
        for (int j = 0; j < 8; ++j)
            GLOAD16(Vb + (size_t)(j * 8 + r8) * TLEN + kv0 + ((c8 ^ r8) << 3),
                    vbuf + j * 1024 + lane * 16);
    };
    auto loadK = [&](int s, short8* kf) {
        const int kv0 = s * 64;
        #pragma unroll
        for (int h2 = 0; h2 < 2; ++h2)
            #pragma unroll
            for (int kt = 0; kt < 2; ++kt) {
                const short* kp = Kb + (size_t)(kv0 + h2 * 32 + kt * 16 + lr) * HDIM + lg * 8;
                kf[(h2 * 2 + kt) * 2]     = *(const short8*)kp;
                kf[(h2 * 2 + kt) * 2 + 1] = *(const short8*)(kp + 32);
            }
    };
    auto readV = [&](short8* vf) {
        #pragma unroll
        for (int h2 = 0; h2 < 2; ++h2)
            #pragma unroll
            for (int ht = 0; ht < 4; ++ht) {
                int row = ht * 16 + lr;
                vf[h2 * 4 + ht] = *(const short8*)(
                    vbuf + row * 128 + (((h2 * 4 + lg) ^ (lr & 7)) << 4));
            }
    };

    // Q B-operand fragments: col = q = lr, k = h
    short8 qf0 = *(const short8*)(Q + base + (size_t)(q0 + lr) * HDIM + lg * 8);
    short8 qf1 = *(const short8*)(Q + base + (size_t)(q0 + lr) * HDIM + 32 + lg * 8);

    f32x4 o[4];
    #pragma unroll
    for (int ht = 0; ht < 4; ++ht) o[ht] = f32x4{0.f, 0.f, 0.f, 0.f};
    float m = -1e30f, l = 0.f;

    auto compute = [&](int s, const short8* kf, const short8* vf) {
        const int kv0 = s * 64;
        // S^T = K Q^T : rows = kv, cols = q (log2 units)
        f32x4 st[2][2];
        #pragma unroll
        for (int h2 = 0; h2 < 2; ++h2)
            #pragma unroll
            for (int kt = 0; kt < 2; ++kt) {
                f32x4 a = f32x4{0.f, 0.f, 0.f, 0.f};
                a = __builtin_amdgcn_mfma_f32_16x16x32_bf16(kf[(h2*2+kt)*2],     qf0, a, 0, 0, 0);
                a = __builtin_amdgcn_mfma_f32_16x16x32_bf16(kf[(h2*2+kt)*2 + 1], qf1, a, 0, 0, 0);
                st[h2][kt] = a;
            }
        if (s == nsup - 1) {              // diagonal supertile: mask kv > q
            const int q = q0 + lr;
            #pragma unroll
            for (int h2 = 0; h2 < 2; ++h2)
                #pragma unroll
                for (int kt = 0; kt < 2; ++kt)
                    #pragma unroll
                    for (int i = 0; i < 4; ++i)
                        if (kv0 + h2 * 32 + kt * 16 + lg * 4 + i > q)
                            st[h2][kt][i] = -1e30f;
        }
        // online softmax (base 2): in-lane over 16 vals + 2 shfl
        float tm = -1e30f;
        #pragma unroll
        for (int h2 = 0; h2 < 2; ++h2)
            #pragma unroll
            for (int kt = 0; kt < 2; ++kt)
                #pragma unroll
                for (int i = 0; i < 4; ++i) tm = fmaxf(tm, st[h2][kt][i]);
        tm = fmaxf(tm, __shfl_xor(tm, 16));
        tm = fmaxf(tm, __shfl_xor(tm, 32));
        float mn = fmaxf(m, tm);
        float fs = EXP2(m - mn);
        m = mn;
        float ls = 0.f;
        #pragma unroll
        for (int h2 = 0; h2 < 2; ++h2)
            #pragma unroll
            for (int kt = 0; kt < 2; ++kt)
                #pragma unroll
                for (int i = 0; i < 4; ++i) {
                    float e = EXP2(st[h2][kt][i] - mn);
                    st[h2][kt][i] = e;
                    ls += e;
                }
        ls += __shfl_xor(ls, 16);
        ls += __shfl_xor(ls, 32);
        l = l * fs + ls;
        #pragma unroll
        for (int ht = 0; ht < 4; ++ht)
            #pragma unroll
            for (int i = 0; i < 4; ++i) o[ht][i] *= fs;
        // pack P -> per-wave swizzled LDS, then B-frag reads
        #pragma unroll
        for (int h2 = 0; h2 < 2; ++h2)
            #pragma unroll
            for (int kt = 0; kt < 2; ++kt) {
                uint2 u;
                u.x = cvtpk(st[h2][kt][0], st[h2][kt][1]);
                u.y = cvtpk(st[h2][kt][2], st[h2][kt][3]);
                *(uint2*)(myPs + lr * 128 + ((h2 * 64 + kt * 32 + lg * 8) ^ swz)) = u;
            }
        short8 pb0 = *(short8*)(myPs + lr * 128 + ((lg * 16) ^ swz));
        short8 pb1 = *(short8*)(myPs + lr * 128 + ((64 + lg * 16) ^ swz));
        // O^T += V^T P
        #pragma unroll
        for (int h2 = 0; h2 < 2; ++h2) {
            short8 pb = h2 ? pb1 : pb0;
            #pragma unroll
            for (int ht = 0; ht < 4; ++ht)
                o[ht] = __builtin_amdgcn_mfma_f32_16x16x32_bf16(
                    vf[h2 * 4 + ht], pb, o[ht], 0, 0, 0);
        }
    };

    // ---- software-pipelined loop, explicit two-phase ping-pong ----
    short8 kfA[8], kfB[8];
    int s = w;
    if (s < nsup) { loadK(s, kfA); stageV(s); }
    while (s < nsup) {
        // phase A: compute s with kfA, prefetch s+4 into kfB
        asm volatile("s_waitcnt vmcnt(0)" ::: "memory");   // kfA + V(s) ready
        __builtin_amdgcn_sched_barrier(0);
        short8 vf[8];
        readV(vf);
        asm volatile("s_waitcnt lgkmcnt(0)" ::: "memory"); // vf in regs
        __builtin_amdgcn_sched_barrier(0);
        if (s + 4 < nsup) { loadK(s + 4, kfB); stageV(s + 4); }
        __builtin_amdgcn_sched_barrier(0);                 // pin prefetch issue
        compute(s, kfA, vf);
        s += 4;
        if (s >= nsup) break;
        // phase B: compute s with kfB, prefetch s+4 into kfA
        asm volatile("s_waitcnt vmcnt(0)" ::: "memory");
        __builtin_amdgcn_sched_barrier(0);
        readV(vf);
        asm volatile("s_waitcnt lgkmcnt(0)" ::: "memory");
        __builtin_amdgcn_sched_barrier(0);
        if (s + 4 < nsup) { loadK(s + 4, kfA); stageV(s + 4); }
        __builtin_amdgcn_sched_barrier(0);
        compute(s, kfB, vf);
        s += 4;
    }

    __syncthreads();   // all waves done with V arena -> reuse for merge
    float* Om = &arena[0][0];                 // [4][16*68] = 17408 B
    float* ml = &arena[0][0] + 4 * 16 * 68;   // [4][2][16] = 512 B
    {
        float* om = Om + w * 16 * 68;
        #pragma unroll
        for (int ht = 0; ht < 4; ++ht)
            *(f32x4*)(om + lr * 68 + ht * 16 + lg * 4) = o[ht];
        if (lg == 0) {
            ml[(w * 2 + 0) * 16 + lr] = m;
            ml[(w * 2 + 1) * 16 + lr] = l;
        }
    }
    __syncthreads();
    // merge 4 partials: thread (w,lane) handles q = lr, h = w*16 + lg*4 ..
    {
        float mp[4], fp[4];
        float mm = -1e30f;
        #pragma unroll
        for (int p = 0; p < 4; ++p) { mp[p] = ml[(p * 2 + 0) * 16 + lr]; mm = fmaxf(mm, mp[p]); }
        float lsum = 0.f;
        #pragma unroll
        for (int p = 0; p < 4; ++p) {
            fp[p] = EXP2(mp[p] - mm);
            lsum += ml[(p * 2 + 1) * 16 + lr] * fp[p];
        }
        float inv = 1.0f / lsum;
        const int off = lr * 68 + w * 16 + lg * 4;
        f32x4 r = f32x4{0.f, 0.f, 0.f, 0.f};
        #pragma unroll
        for (int p = 0; p < 4; ++p) {
            f32x4 v = *(const f32x4*)(Om + p * 16 * 68 + off);
            #pragma unroll
            for (int i = 0; i < 4; ++i) r[i] += v[i] * fp[p];
        }
        #pragma unroll
        for (int i = 0; i < 4; ++i) r[i] *= inv;
        *(f32x4*)(O + base + (size_t)(q0 + lr) * HDIM + w * 16 + lg * 4) = r;
    }
}

// ---------------------------------------------------------------------------
extern "C" void kernel_launch(void* const* d_in, const int* in_sizes, int n_in,
                              void* d_out, int out_size, void* d_ws, size_t ws_size,
                              hipStream_t stream) {
    const float* x  = (const float*)d_in[0];
    const float* Wq = (const float*)d_in[1];
    const float* Wk = (const float*)d_in[2];
    const float* Wv = (const float*)d_in[3];
    float* out = (float*)d_out;

    char* ws = (char*)d_ws;
    short* Q  = (short*)(ws);
    short* K  = (short*)(ws + (size_t)2 * 1024 * 1024);
    short* Vt = (short*)(ws + (size_t)4 * 1024 * 1024);
    short* Wt = (short*)(ws + (size_t)6 * 1024 * 1024);

    wt_kernel<<<dim3(16, 3), 256, 0, stream>>>(Wq, Wk, Wv, Wt);
    qkv_kernel<<<BT / 32, 256, 0, stream>>>(x, Wt, Q, K, Vt);
    attn_kernel<<<dim3(BATCH, TLEN / 16), 256, 0, stream>>>(Q, K, Vt, out);
}

// Round 11
// 149.107 us; speedup vs baseline: 1.1972x; 1.1972x over previous
//
#include <hip/hip_runtime.h>
#include <hip/hip_bf16.h>

// Problem constants
#define BATCH 8
#define TLEN 2048
#define CDIM 1024
#define HDIM 64
#define BT (BATCH * TLEN)   // 16384

typedef __attribute__((ext_vector_type(8))) short short8;
typedef __attribute__((ext_vector_type(4))) float f32x4;

#define GLOAD16(gsrc, lds) __builtin_amdgcn_global_load_lds( \
    (const __attribute__((address_space(1))) void*)(gsrc),   \
    (__attribute__((address_space(3))) void*)(lds), 16, 0, 0)

#if __has_builtin(__builtin_amdgcn_exp2f)
#define EXP2(x) __builtin_amdgcn_exp2f(x)
#else
#define EXP2(x) exp2f(x)
#endif

// round-to-nearest-even f32 -> bf16 (bit pattern)
__device__ inline unsigned bfbits(float f) {
    unsigned u = __builtin_bit_cast(unsigned, f);
    return (u + 0x7fffu + ((u >> 16) & 1u)) >> 16;
}
__device__ inline short bf1(float f) { return (short)bfbits(f); }
// packed f32x2 -> bf16x2 via HW instruction (src0 -> low half)
__device__ inline unsigned cvtpk(float lo, float hi) {
    unsigned r;
    asm("v_cvt_pk_bf16_f32 %0, %1, %2" : "=v"(r) : "v"(lo), "v"(hi));
    return r;
}

// ---------------------------------------------------------------------------
// Kernel 0: transpose + bf16-cast weights. Wt[3][64 n][1024 k] = W[k][n].
// Folds attention scale AND log2(e) into Wq (softmax runs in base 2).
// ---------------------------------------------------------------------------
__global__ __launch_bounds__(256) void wt_kernel(
        const float* __restrict__ Wq, const float* __restrict__ Wk,
        const float* __restrict__ Wv, short* __restrict__ Wt) {
    const int kc = blockIdx.x * 64;
    const int wi = blockIdx.y;
    const float* W = (wi == 0) ? Wq : ((wi == 1) ? Wk : Wv);
    const float scale = (wi == 0) ? 0.125f * 1.44269504088896f : 1.0f;
    __shared__ short tile[64][65];
    const int t = threadIdx.x;
    #pragma unroll
    for (int i = 0; i < 16; ++i) {
        int flat = i * 256 + t;
        int kk = flat >> 6, n = flat & 63;
        tile[kk][n] = bf1(W[(size_t)(kc + kk) * HDIM + n] * scale);
    }
    __syncthreads();
    const int n = t >> 2, c0 = (t & 3) * 16;
    #pragma unroll
    for (int i = 0; i < 16; ++i)
        Wt[((size_t)wi * 64 + n) * CDIM + kc + c0 + i] = tile[c0 + i][n];
}

// ---------------------------------------------------------------------------
// Kernel 1: QKV projection, 32 rows/block (512 blocks), 2-phase pipelined
// with COUNTED vmcnt (T4): stage(next) issued before the barrier stays in
// flight across it. Outputs: Q,K row-major [t][64]; V transposed Vt[b][h][t].
// ---------------------------------------------------------------------------
__global__ __launch_bounds__(256) void qkv_kernel(
        const float* __restrict__ x, const short* __restrict__ Wt,
        short* __restrict__ Q, short* __restrict__ K, short* __restrict__ Vt) {
    __shared__ float xs[2][32 * 64];      // 2 x 8 KB, swizzled
    __shared__ short wl[2][3 * 64 * 64];  // 2 x 24 KB, swizzled
    __shared__ short ob[32 * 72];         // epilogue staging (padded)
    const int t = threadIdx.x;
    const int lane = t & 63, w = t >> 6;
    const int lr = lane & 15, lg = lane >> 4;
    const int r0 = blockIdx.x * 32;

    auto stage = [&](int buf, int kc) {   // 8 global_load_lds per thread
        #pragma unroll
        for (int i = 0; i < 2; ++i) {
            int chunk = t + 256 * i;
            int row = chunk >> 4, slot = chunk & 15;
            GLOAD16(x + (size_t)(r0 + row) * CDIM + kc + ((slot ^ (row & 7)) << 2),
                    xs[buf] + chunk * 4);
        }
        #pragma unroll
        for (int i = 0; i < 6; ++i) {
            int chunk = t + 256 * i;
            int R = chunk >> 3, slot = chunk & 7;
            GLOAD16(Wt + (size_t)R * CDIM + kc + ((slot ^ (R & 7)) << 3),
                    wl[buf] + chunk * 8);
        }
    };

    f32x4 acc[3][2];
    #pragma unroll
    for (int wi = 0; wi < 3; ++wi)
        #pragma unroll
        for (int rt = 0; rt < 2; ++rt) acc[wi][rt] = f32x4{0.f, 0.f, 0.f, 0.f};

    stage(0, 0);
    int cur = 0;
    for (int kc = 0; kc < CDIM; kc += 64) {
        if (kc + 64 < CDIM) {
            stage(cur ^ 1, kc + 64);      // 8 new loads -> 16 outstanding
            asm volatile("s_waitcnt vmcnt(8)" ::: "memory");  // cur's 8 done
        } else {
            asm volatile("s_waitcnt vmcnt(0)" ::: "memory");  // drain last
        }
        __builtin_amdgcn_s_barrier();
        asm volatile("" ::: "memory");
        const float* xsc = xs[cur];
        const short* wlc = wl[cur];

        short8 af[2][2];
        #pragma unroll
        for (int rt = 0; rt < 2; ++rt)
            #pragma unroll
            for (int ks = 0; ks < 2; ++ks) {
                int row = rt * 16 + lr;
                int s0 = ks * 8 + lg * 2;
                f32x4 a0 = *(const f32x4*)(xsc + row * 64 + (((s0)     ^ (row & 7)) << 2));
                f32x4 a1 = *(const f32x4*)(xsc + row * 64 + (((s0 + 1) ^ (row & 7)) << 2));
                uint4 uu;
                uu.x = cvtpk(a0[0], a0[1]); uu.y = cvtpk(a0[2], a0[3]);
                uu.z = cvtpk(a1[0], a1[1]); uu.w = cvtpk(a1[2], a1[3]);
                af[rt][ks] = __builtin_bit_cast(short8, uu);
            }
        #pragma unroll
        for (int wi = 0; wi < 3; ++wi)
            #pragma unroll
            for (int ks = 0; ks < 2; ++ks) {
                int R = wi * 64 + w * 16 + lr;
                short8 bfv = *(const short8*)(wlc + R * 64 + (((ks * 4 + lg) ^ (lr & 7)) << 3));
                #pragma unroll
                for (int rt = 0; rt < 2; ++rt)
                    acc[wi][rt] = __builtin_amdgcn_mfma_f32_16x16x32_bf16(
                        af[rt][ks], bfv, acc[wi][rt], 0, 0, 0);
            }
        __builtin_amdgcn_s_barrier();
        cur ^= 1;
    }
    // V epilogue: C/D rows are consecutive t -> pack pairs, 8B stores to Vt[b][h][t]
    {
        const int bb = r0 >> 11, t0 = r0 & 2047;
        #pragma unroll
        for (int rt = 0; rt < 2; ++rt) {
            uint2 uv;
            uv.x = cvtpk(acc[2][rt][0], acc[2][rt][1]);
            uv.y = cvtpk(acc[2][rt][2], acc[2][rt][3]);
            *(uint2*)(Vt + ((size_t)bb * HDIM + w * 16 + lr) * TLEN + t0 + rt * 16 + lg * 4) = uv;
        }
    }
    // Q, K epilogue via LDS transpose -> coalesced short8 stores
    #pragma unroll
    for (int wi = 0; wi < 2; ++wi) {
        __syncthreads();
        #pragma unroll
        for (int rt = 0; rt < 2; ++rt)
            #pragma unroll
            for (int i = 0; i < 4; ++i)
                ob[(rt * 16 + lg * 4 + i) * 72 + w * 16 + lr] = bf1(acc[wi][rt][i]);
        __syncthreads();
        int row = t >> 3, c0 = (t & 7) * 8;
        short8 v = *(short8*)(ob + row * 72 + c0);
        short* dst = (wi == 0) ? Q : K;
        *(short8*)(dst + (size_t)(r0 + row) * HDIM + c0) = v;
    }
}

// ---------------------------------------------------------------------------
// Kernel 2: flash attention v3 -- cooperative block, causal, swapped QK^T,
// base-2 softmax. One 64-row q-tile per block; grid (8,32) = 256 blocks =
// 1/CU. Wave w owns q rows [q0+w*16, +16); ALL waves consume the SAME
// supertile stream s = 0..qi from block-shared double-buffered K+V LDS
// (T3/T4: counted vmcnt(4), prefetch in flight across barriers, 2
// barriers/iter). Perfect intra-block balance; no merge phase (each wave
// holds complete rows -> in-lane normalize + direct store).
// K and V tiles: 64x64 bf16, XOR-swizzled (pre-swizzled global source,
// linear gload_lds dest, swizzled ds_read_b128 -- rule #21 / T2).
// ---------------------------------------------------------------------------
__global__ __launch_bounds__(256) void attn_kernel(
        const short* __restrict__ Q, const short* __restrict__ K,
        const short* __restrict__ Vt, float* __restrict__ O) {
    __shared__ short kbuf[2][64 * 64];   // 2 x 8 KB
    __shared__ short vbuf[2][64 * 64];   // 2 x 8 KB
    __shared__ short Ps[4][16 * 64];     // per-wave P buffer (8 KB)
    const int t = threadIdx.x, lane = t & 63, w = t >> 6;
    const int lr = lane & 15, lg = lane >> 4;
    const int b = blockIdx.x;
    const int qi = blockIdx.y;
    const int q0 = qi * 64;
    const size_t base = (size_t)b * TLEN * HDIM;
    const short* Kb = K + base;
    const short* Vb = Vt + base;    // same per-batch stride (64*2048)
    char* myPs = (char*)Ps[w];
    const int swz = (lr & 7) << 4;  // byte XOR within 128B row (P buffer)
    const int q = q0 + w * 16 + lr; // this lane's q row

    // stage supertile s into buffer p: K rows are contiguous 8KB, V rows
    // stride TLEN. 2 chunks per tensor per thread (chunk = 16B slot).
    auto stageKV = [&](int s, int p) {
        const int kv0 = s * 64;
        #pragma unroll
        for (int j = 0; j < 2; ++j) {
            int c = t + 256 * j;
            int row = c >> 3, slot = c & 7;
            int off = (slot ^ (row & 7)) << 3;   // shorts
            GLOAD16(Kb + (size_t)(kv0 + row) * HDIM + off, kbuf[p] + c * 8);
            GLOAD16(Vb + (size_t)row * TLEN + kv0 + off, vbuf[p] + c * 8);
        }
    };

    // Q B-operand fragments: col = q, k = h
    short8 qf0 = *(const short8*)(Q + base + (size_t)q * HDIM + lg * 8);
    short8 qf1 = *(const short8*)(Q + base + (size_t)q * HDIM + 32 + lg * 8);

    f32x4 o[4];
    #pragma unroll
    for (int ht = 0; ht < 4; ++ht) o[ht] = f32x4{0.f, 0.f, 0.f, 0.f};
    float m = -1e30f, l = 0.f;

    stageKV(0, 0);
    for (int s = 0; s <= qi; ++s) {
        const int p = s & 1;
        if (s < qi) {
            stageKV(s + 1, p ^ 1);      // 4 new loads in flight
            asm volatile("s_waitcnt vmcnt(4)" ::: "memory");  // cur's 4 done
        } else {
            asm volatile("s_waitcnt vmcnt(0)" ::: "memory");
        }
        __builtin_amdgcn_s_barrier();
        asm volatile("" ::: "memory");

        const char* kb = (const char*)kbuf[p];
        const char* vb = (const char*)vbuf[p];
        // K fragments (A rows = kv), swizzled ds_read_b128
        short8 kf[8];
        #pragma unroll
        for (int h2 = 0; h2 < 2; ++h2)
            #pragma unroll
            for (int kt = 0; kt < 2; ++kt) {
                int R = h2 * 32 + kt * 16 + lr;
                #pragma unroll
                for (int ks = 0; ks < 2; ++ks)
                    kf[(h2 * 2 + kt) * 2 + ks] = *(const short8*)(
                        kb + R * 128 + (((ks * 4 + lg) ^ (lr & 7)) << 4));
            }
        // V fragments (A rows = h)
        short8 vf[8];
        #pragma unroll
        for (int h2 = 0; h2 < 2; ++h2)
            #pragma unroll
            for (int ht = 0; ht < 4; ++ht) {
                int row = ht * 16 + lr;
                vf[h2 * 4 + ht] = *(const short8*)(
                    vb + row * 128 + (((h2 * 4 + lg) ^ (lr & 7)) << 4));
            }
        asm volatile("s_waitcnt lgkmcnt(0)" ::: "memory");
        __builtin_amdgcn_sched_barrier(0);

        const int kv0 = s * 64;
        // S^T = K Q^T : rows = kv, cols = q (log2 units)
        f32x4 st[2][2];
        #pragma unroll
        for (int h2 = 0; h2 < 2; ++h2)
            #pragma unroll
            for (int kt = 0; kt < 2; ++kt) {
                f32x4 a = f32x4{0.f, 0.f, 0.f, 0.f};
                a = __builtin_amdgcn_mfma_f32_16x16x32_bf16(kf[(h2*2+kt)*2],     qf0, a, 0, 0, 0);
                a = __builtin_amdgcn_mfma_f32_16x16x32_bf16(kf[(h2*2+kt)*2 + 1], qf1, a, 0, 0, 0);
                st[h2][kt] = a;
            }
        if (s == qi) {                    // diagonal supertile: mask kv > q
            #pragma unroll
            for (int h2 = 0; h2 < 2; ++h2)
                #pragma unroll
                for (int kt = 0; kt < 2; ++kt)
                    #pragma unroll
                    for (int i = 0; i < 4; ++i)
                        if (kv0 + h2 * 32 + kt * 16 + lg * 4 + i > q)
                            st[h2][kt][i] = -1e30f;
        }
        // online softmax (base 2) for q row: in-lane over 16 vals + 2 shfl
        float tm = -1e30f;
        #pragma unroll
        for (int h2 = 0; h2 < 2; ++h2)
            #pragma unroll
            for (int kt = 0; kt < 2; ++kt)
                #pragma unroll
                for (int i = 0; i < 4; ++i) tm = fmaxf(tm, st[h2][kt][i]);
        tm = fmaxf(tm, __shfl_xor(tm, 16));
        tm = fmaxf(tm, __shfl_xor(tm, 32));
        float mn = fmaxf(m, tm);
        float fs = EXP2(m - mn);
        m = mn;
        float ls = 0.f;
        #pragma unroll
        for (int h2 = 0; h2 < 2; ++h2)
            #pragma unroll
            for (int kt = 0; kt < 2; ++kt)
                #pragma unroll
                for (int i = 0; i < 4; ++i) {
                    float e = EXP2(st[h2][kt][i] - mn);
                    st[h2][kt][i] = e;
                    ls += e;
                }
        ls += __shfl_xor(ls, 16);
        ls += __shfl_xor(ls, 32);
        l = l * fs + ls;
        #pragma unroll
        for (int ht = 0; ht < 4; ++ht)
            #pragma unroll
            for (int i = 0; i < 4; ++i) o[ht][i] *= fs;
        // pack P -> per-wave swizzled LDS, then B-frag reads
        #pragma unroll
        for (int h2 = 0; h2 < 2; ++h2)
            #pragma unroll
            for (int kt = 0; kt < 2; ++kt) {
                uint2 u;
                u.x = cvtpk(st[h2][kt][0], st[h2][kt][1]);
                u.y = cvtpk(st[h2][kt][2], st[h2][kt][3]);
                *(uint2*)(myPs + lr * 128 + ((h2 * 64 + kt * 32 + lg * 8) ^ swz)) = u;
            }
        short8 pb0 = *(short8*)(myPs + lr * 128 + ((lg * 16) ^ swz));
        short8 pb1 = *(short8*)(myPs + lr * 128 + ((64 + lg * 16) ^ swz));
        // O^T += V^T P
        #pragma unroll
        for (int h2 = 0; h2 < 2; ++h2) {
            short8 pb = h2 ? pb1 : pb0;
            #pragma unroll
            for (int ht = 0; ht < 4; ++ht)
                o[ht] = __builtin_amdgcn_mfma_f32_16x16x32_bf16(
                    vf[h2 * 4 + ht], pb, o[ht], 0, 0, 0);
        }
        __builtin_amdgcn_s_barrier();   // all waves done with buf p
    }
    // epilogue: in-lane normalize, direct store (lane holds O[q][ht*16+lg*4+i])
    {
        float inv = 1.0f / l;
        float* dst = O + base + (size_t)q * HDIM;
        #pragma unroll
        for (int ht = 0; ht < 4; ++ht) {
            f32x4 r;
            #pragma unroll
            for (int i = 0; i < 4; ++i) r[i] = o[ht][i] * inv;
            *(f32x4*)(dst + ht * 16 + lg * 4) = r;
        }
    }
}

// ---------------------------------------------------------------------------
extern "C" void kernel_launch(void* const* d_in, const int* in_sizes, int n_in,
                              void* d_out, int out_size, void* d_ws, size_t ws_size,
                              hipStream_t stream) {
    const float* x  = (const float*)d_in[0];
    const float* Wq = (const float*)d_in[1];
    const float* Wk = (const float*)d_in[2];
    const float* Wv = (const float*)d_in[3];
    float* out = (float*)d_out;

    char* ws = (char*)d_ws;
    short* Q  = (short*)(ws);
    short* K  = (short*)(ws + (size_t)2 * 1024 * 1024);
    short* Vt = (short*)(ws + (size_t)4 * 1024 * 1024);
    short* Wt = (short*)(ws + (size_t)6 * 1024 * 1024);

    wt_kernel<<<dim3(16, 3), 256, 0, stream>>>(Wq, Wk, Wv, Wt);
    qkv_kernel<<<BT / 32, 256, 0, stream>>>(x, Wt, Q, K, Vt);
    attn_kernel<<<dim3(BATCH, TLEN / 64), 256, 0, stream>>>(Q, K, Vt, out);
}

// Round 13
// 136.948 us; speedup vs baseline: 1.3035x; 1.0888x over previous
//
#include <hip/hip_runtime.h>
#include <hip/hip_bf16.h>

// Problem constants
#define BATCH 8
#define TLEN 2048
#define CDIM 1024
#define HDIM 64
#define BT (BATCH * TLEN)   // 16384

typedef __attribute__((ext_vector_type(8))) short short8;
typedef __attribute__((ext_vector_type(4))) float f32x4;

#define GLOAD16(gsrc, lds) __builtin_amdgcn_global_load_lds( \
    (const __attribute__((address_space(1))) void*)(gsrc),   \
    (__attribute__((address_space(3))) void*)(lds), 16, 0, 0)

#if __has_builtin(__builtin_amdgcn_exp2f)
#define EXP2(x) __builtin_amdgcn_exp2f(x)
#else
#define EXP2(x) exp2f(x)
#endif

// round-to-nearest-even f32 -> bf16 (bit pattern)
__device__ inline unsigned bfbits(float f) {
    unsigned u = __builtin_bit_cast(unsigned, f);
    return (u + 0x7fffu + ((u >> 16) & 1u)) >> 16;
}
__device__ inline short bf1(float f) { return (short)bfbits(f); }
// packed f32x2 -> bf16x2 via HW instruction (src0 -> low half)
__device__ inline unsigned cvtpk(float lo, float hi) {
    unsigned r;
    asm("v_cvt_pk_bf16_f32 %0, %1, %2" : "=v"(r) : "v"(lo), "v"(hi));
    return r;
}

// ---------------------------------------------------------------------------
// Kernel 0: transpose + bf16-cast weights. Wt[3][64 n][1024 k] = W[k][n].
// Folds attention scale AND log2(e) into Wq (softmax runs in base 2).
// ---------------------------------------------------------------------------
__global__ __launch_bounds__(256) void wt_kernel(
        const float* __restrict__ Wq, const float* __restrict__ Wk,
        const float* __restrict__ Wv, short* __restrict__ Wt) {
    const int kc = blockIdx.x * 64;
    const int wi = blockIdx.y;
    const float* W = (wi == 0) ? Wq : ((wi == 1) ? Wk : Wv);
    const float scale = (wi == 0) ? 0.125f * 1.44269504088896f : 1.0f;
    __shared__ short tile[64][65];
    const int t = threadIdx.x;
    #pragma unroll
    for (int i = 0; i < 16; ++i) {
        int flat = i * 256 + t;
        int kk = flat >> 6, n = flat & 63;
        tile[kk][n] = bf1(W[(size_t)(kc + kk) * HDIM + n] * scale);
    }
    __syncthreads();
    const int n = t >> 2, c0 = (t & 3) * 16;
    #pragma unroll
    for (int i = 0; i < 16; ++i)
        Wt[((size_t)wi * 64 + n) * CDIM + kc + c0 + i] = tile[c0 + i][n];
}

// ---------------------------------------------------------------------------
// Kernel 1: QKV projection, 32 rows/block (512 blocks), 2-phase pipelined
// with COUNTED vmcnt (T4). Outputs: Q,K row-major [t][64]; Vt[b][h][t].
// ---------------------------------------------------------------------------
__global__ __launch_bounds__(256) void qkv_kernel(
        const float* __restrict__ x, const short* __restrict__ Wt,
        short* __restrict__ Q, short* __restrict__ K, short* __restrict__ Vt) {
    __shared__ float xs[2][32 * 64];      // 2 x 8 KB, swizzled
    __shared__ short wl[2][3 * 64 * 64];  // 2 x 24 KB, swizzled
    __shared__ short ob[32 * 72];         // epilogue staging (padded)
    const int t = threadIdx.x;
    const int lane = t & 63, w = t >> 6;
    const int lr = lane & 15, lg = lane >> 4;
    const int r0 = blockIdx.x * 32;

    auto stage = [&](int buf, int kc) {   // 8 global_load_lds per thread
        #pragma unroll
        for (int i = 0; i < 2; ++i) {
            int chunk = t + 256 * i;
            int row = chunk >> 4, slot = chunk & 15;
            GLOAD16(x + (size_t)(r0 + row) * CDIM + kc + ((slot ^ (row & 7)) << 2),
                    xs[buf] + chunk * 4);
        }
        #pragma unroll
        for (int i = 0; i < 6; ++i) {
            int chunk = t + 256 * i;
            int R = chunk >> 3, slot = chunk & 7;
            GLOAD16(Wt + (size_t)R * CDIM + kc + ((slot ^ (R & 7)) << 3),
                    wl[buf] + chunk * 8);
        }
    };

    f32x4 acc[3][2];
    #pragma unroll
    for (int wi = 0; wi < 3; ++wi)
        #pragma unroll
        for (int rt = 0; rt < 2; ++rt) acc[wi][rt] = f32x4{0.f, 0.f, 0.f, 0.f};

    stage(0, 0);
    int cur = 0;
    for (int kc = 0; kc < CDIM; kc += 64) {
        if (kc + 64 < CDIM) {
            stage(cur ^ 1, kc + 64);      // 8 new loads -> 16 outstanding
            asm volatile("s_waitcnt vmcnt(8)" ::: "memory");  // cur's 8 done
        } else {
            asm volatile("s_waitcnt vmcnt(0)" ::: "memory");  // drain last
        }
        __builtin_amdgcn_s_barrier();
        asm volatile("" ::: "memory");
        const float* xsc = xs[cur];
        const short* wlc = wl[cur];

        short8 af[2][2];
        #pragma unroll
        for (int rt = 0; rt < 2; ++rt)
            #pragma unroll
            for (int ks = 0; ks < 2; ++ks) {
                int row = rt * 16 + lr;
                int s0 = ks * 8 + lg * 2;
                f32x4 a0 = *(const f32x4*)(xsc + row * 64 + (((s0)     ^ (row & 7)) << 2));
                f32x4 a1 = *(const f32x4*)(xsc + row * 64 + (((s0 + 1) ^ (row & 7)) << 2));
                uint4 uu;
                uu.x = cvtpk(a0[0], a0[1]); uu.y = cvtpk(a0[2], a0[3]);
                uu.z = cvtpk(a1[0], a1[1]); uu.w = cvtpk(a1[2], a1[3]);
                af[rt][ks] = __builtin_bit_cast(short8, uu);
            }
        #pragma unroll
        for (int wi = 0; wi < 3; ++wi)
            #pragma unroll
            for (int ks = 0; ks < 2; ++ks) {
                int R = wi * 64 + w * 16 + lr;
                short8 bfv = *(const short8*)(wlc + R * 64 + (((ks * 4 + lg) ^ (lr & 7)) << 3));
                #pragma unroll
                for (int rt = 0; rt < 2; ++rt)
                    acc[wi][rt] = __builtin_amdgcn_mfma_f32_16x16x32_bf16(
                        af[rt][ks], bfv, acc[wi][rt], 0, 0, 0);
            }
        __builtin_amdgcn_s_barrier();
        cur ^= 1;
    }
    // V epilogue: pack pairs, 8B stores to Vt[b][h][t]
    {
        const int bb = r0 >> 11, t0 = r0 & 2047;
        #pragma unroll
        for (int rt = 0; rt < 2; ++rt) {
            uint2 uv;
            uv.x = cvtpk(acc[2][rt][0], acc[2][rt][1]);
            uv.y = cvtpk(acc[2][rt][2], acc[2][rt][3]);
            *(uint2*)(Vt + ((size_t)bb * HDIM + w * 16 + lr) * TLEN + t0 + rt * 16 + lg * 4) = uv;
        }
    }
    // Q, K epilogue via LDS transpose -> coalesced short8 stores
    #pragma unroll
    for (int wi = 0; wi < 2; ++wi) {
        __syncthreads();
        #pragma unroll
        for (int rt = 0; rt < 2; ++rt)
            #pragma unroll
            for (int i = 0; i < 4; ++i)
                ob[(rt * 16 + lg * 4 + i) * 72 + w * 16 + lr] = bf1(acc[wi][rt][i]);
        __syncthreads();
        int row = t >> 3, c0 = (t & 7) * 8;
        short8 v = *(short8*)(ob + row * 72 + c0);
        short* dst = (wi == 0) ? Q : K;
        *(short8*)(dst + (size_t)(r0 + row) * HDIM + c0) = v;
    }
}

// ---------------------------------------------------------------------------
// Kernel 2: flash attention v4 -- cooperative block + kv-SPLIT.
// Block (b, y): q-tile qi = 31 - (y>>1) (heavy first), half = y&1;
// processes supertiles s = half, half+2, ... <= qi from block-shared
// double-buffered K+V LDS (counted vmcnt(8), 2 barriers/iter). 512 blocks
// = 2/CU -> sibling block hides barrier/LDS stalls; critical path 16 iters
// (was 32). Partial (O, m, l) per block -> workspace; attn_merge combines.
// ---------------------------------------------------------------------------
__global__ __launch_bounds__(256) void attn_kernel(
        const short* __restrict__ Q, const short* __restrict__ K,
        const short* __restrict__ Vt, float* __restrict__ Opart,
        float* __restrict__ Mlp) {
    __shared__ short kbuf[2][64 * 64];   // 2 x 8 KB
    __shared__ short vbuf[2][64 * 64];   // 2 x 8 KB
    __shared__ short Ps[4][16 * 64];     // per-wave P buffer (8 KB)
    const int t = threadIdx.x, lane = t & 63, w = t >> 6;
    const int lr = lane & 15, lg = lane >> 4;
    const int b = blockIdx.x;
    const int qi = (TLEN / 64 - 1) - (blockIdx.y >> 1);   // heavy first
    const int half = blockIdx.y & 1;
    const int q0 = qi * 64;
    const size_t base = (size_t)b * TLEN * HDIM;
    const short* Kb = K + base;
    const short* Vb = Vt + base;
    char* myPs = (char*)Ps[w];
    const int swz = (lr & 7) << 4;
    const int q = q0 + w * 16 + lr;

    auto stageKV = [&](int s, int p) {
        const int kv0 = s * 64;
        #pragma unroll
        for (int j = 0; j < 2; ++j) {
            int c = t + 256 * j;
            int row = c >> 3, slot = c & 7;
            int off = (slot ^ (row & 7)) << 3;   // shorts
            GLOAD16(Kb + (size_t)(kv0 + row) * HDIM + off, kbuf[p] + c * 8);
            GLOAD16(Vb + (size_t)row * TLEN + kv0 + off, vbuf[p] + c * 8);
        }
    };

    short8 qf0 = *(const short8*)(Q + base + (size_t)q * HDIM + lg * 8);
    short8 qf1 = *(const short8*)(Q + base + (size_t)q * HDIM + 32 + lg * 8);

    f32x4 o[4];
    #pragma unroll
    for (int ht = 0; ht < 4; ++ht) o[ht] = f32x4{0.f, 0.f, 0.f, 0.f};
    float m = -1e30f, l = 0.f;

    if (half <= qi) stageKV(half, 0);
    int pp = 0;
    for (int s = half; s <= qi; s += 2) {
        if (s + 2 <= qi) {
            stageKV(s + 2, pp ^ 1);     // 8 new loads -> 16 outstanding
            asm volatile("s_waitcnt vmcnt(8)" ::: "memory");  // cur's 8 done
        } else {
            asm volatile("s_waitcnt vmcnt(0)" ::: "memory");
        }
        __builtin_amdgcn_s_barrier();
        asm volatile("" ::: "memory");

        const char* kb = (const char*)kbuf[pp];
        const char* vb = (const char*)vbuf[pp];
        short8 kf[8];
        #pragma unroll
        for (int h2 = 0; h2 < 2; ++h2)
            #pragma unroll
            for (int kt = 0; kt < 2; ++kt) {
                int R = h2 * 32 + kt * 16 + lr;
                #pragma unroll
                for (int ks = 0; ks < 2; ++ks)
                    kf[(h2 * 2 + kt) * 2 + ks] = *(const short8*)(
                        kb + R * 128 + (((ks * 4 + lg) ^ (lr & 7)) << 4));
            }
        short8 vf[8];
        #pragma unroll
        for (int h2 = 0; h2 < 2; ++h2)
            #pragma unroll
            for (int ht = 0; ht < 4; ++ht) {
                int row = ht * 16 + lr;
                vf[h2 * 4 + ht] = *(const short8*)(
                    vb + row * 128 + (((h2 * 4 + lg) ^ (lr & 7)) << 4));
            }
        asm volatile("s_waitcnt lgkmcnt(0)" ::: "memory");
        __builtin_amdgcn_sched_barrier(0);

        const int kv0 = s * 64;
        f32x4 st[2][2];
        #pragma unroll
        for (int h2 = 0; h2 < 2; ++h2)
            #pragma unroll
            for (int kt = 0; kt < 2; ++kt) {
                f32x4 a = f32x4{0.f, 0.f, 0.f, 0.f};
                a = __builtin_amdgcn_mfma_f32_16x16x32_bf16(kf[(h2*2+kt)*2],     qf0, a, 0, 0, 0);
                a = __builtin_amdgcn_mfma_f32_16x16x32_bf16(kf[(h2*2+kt)*2 + 1], qf1, a, 0, 0, 0);
                st[h2][kt] = a;
            }
        if (s == qi) {                    // diagonal supertile: mask kv > q
            #pragma unroll
            for (int h2 = 0; h2 < 2; ++h2)
                #pragma unroll
                for (int kt = 0; kt < 2; ++kt)
                    #pragma unroll
                    for (int i = 0; i < 4; ++i)
                        if (kv0 + h2 * 32 + kt * 16 + lg * 4 + i > q)
                            st[h2][kt][i] = -1e30f;
        }
        // online softmax (base 2): in-lane over 16 vals + 2 shfl
        float tm = -1e30f;
        #pragma unroll
        for (int h2 = 0; h2 < 2; ++h2)
            #pragma unroll
            for (int kt = 0; kt < 2; ++kt)
                #pragma unroll
                for (int i = 0; i < 4; ++i) tm = fmaxf(tm, st[h2][kt][i]);
        tm = fmaxf(tm, __shfl_xor(tm, 16));
        tm = fmaxf(tm, __shfl_xor(tm, 32));
        float mn = fmaxf(m, tm);
        float fs = EXP2(m - mn);
        m = mn;
        float ls = 0.f;
        #pragma unroll
        for (int h2 = 0; h2 < 2; ++h2)
            #pragma unroll
            for (int kt = 0; kt < 2; ++kt)
                #pragma unroll
                for (int i = 0; i < 4; ++i) {
                    float e = EXP2(st[h2][kt][i] - mn);
                    st[h2][kt][i] = e;
                    ls += e;
                }
        ls += __shfl_xor(ls, 16);
        ls += __shfl_xor(ls, 32);
        l = l * fs + ls;
        #pragma unroll
        for (int ht = 0; ht < 4; ++ht)
            #pragma unroll
            for (int i = 0; i < 4; ++i) o[ht][i] *= fs;
        // pack P -> per-wave swizzled LDS, then B-frag reads
        #pragma unroll
        for (int h2 = 0; h2 < 2; ++h2)
            #pragma unroll
            for (int kt = 0; kt < 2; ++kt) {
                uint2 u;
                u.x = cvtpk(st[h2][kt][0], st[h2][kt][1]);
                u.y = cvtpk(st[h2][kt][2], st[h2][kt][3]);
                *(uint2*)(myPs + lr * 128 + ((h2 * 64 + kt * 32 + lg * 8) ^ swz)) = u;
            }
        short8 pb0 = *(short8*)(myPs + lr * 128 + ((lg * 16) ^ swz));
        short8 pb1 = *(short8*)(myPs + lr * 128 + ((64 + lg * 16) ^ swz));
        // O^T += V^T P
        #pragma unroll
        for (int h2 = 0; h2 < 2; ++h2) {
            short8 pb = h2 ? pb1 : pb0;
            #pragma unroll
            for (int ht = 0; ht < 4; ++ht)
                o[ht] = __builtin_amdgcn_mfma_f32_16x16x32_bf16(
                    vf[h2 * 4 + ht], pb, o[ht], 0, 0, 0);
        }
        __builtin_amdgcn_s_barrier();
        pp ^= 1;
    }
    // write partial state: Opart[pb][64 rows][64 cols], Mlp[pb][{m:0-63, l:64-127}]
    {
        const int pb = (b * (TLEN / 64) + qi) * 2 + half;
        float* op = Opart + (size_t)pb * 4096 + (w * 16 + lr) * 64;
        #pragma unroll
        for (int ht = 0; ht < 4; ++ht)
            *(f32x4*)(op + ht * 16 + lg * 4) = o[ht];
        if (lg == 0) {
            Mlp[pb * 128 + w * 16 + lr] = m;
            Mlp[pb * 128 + 64 + w * 16 + lr] = l;
        }
    }
}

// ---------------------------------------------------------------------------
// Kernel 3: merge the two kv-halves per q-tile and write final O.
// ---------------------------------------------------------------------------
__global__ __launch_bounds__(256) void attn_merge(
        const float* __restrict__ Opart, const float* __restrict__ Mlp,
        float* __restrict__ O) {
    __shared__ float sf0[64], sf1[64], sinv[64];
    const int t = threadIdx.x;
    const int b = blockIdx.x, qi = blockIdx.y;
    const int pb0 = (b * (TLEN / 64) + qi) * 2;
    const int pb1 = pb0 + 1;
    if (t < 64) {
        float m0 = Mlp[pb0 * 128 + t], l0 = Mlp[pb0 * 128 + 64 + t];
        float m1 = Mlp[pb1 * 128 + t], l1 = Mlp[pb1 * 128 + 64 + t];
        float mm = fmaxf(m0, m1);
        float f0 = EXP2(m0 - mm), f1 = EXP2(m1 - mm);
        float denom = l0 * f0 + l1 * f1;
        sf0[t] = f0; sf1[t] = f1; sinv[t] = 1.0f / denom;
    }
    __syncthreads();
    const float* p0 = Opart + (size_t)pb0 * 4096;
    const float* p1 = Opart + (size_t)pb1 * 4096;
    float* dst = O + ((size_t)b * TLEN + qi * 64) * HDIM;
    #pragma unroll
    for (int j = 0; j < 4; ++j) {
        int flat = j * 256 + t;           // 1024 f32x4 chunks
        int row = flat >> 4, c = (flat & 15) * 4;
        f32x4 a = *(const f32x4*)(p0 + row * 64 + c);
        f32x4 bb = *(const f32x4*)(p1 + row * 64 + c);
        float f0 = sf0[row], f1 = sf1[row], inv = sinv[row];
        f32x4 r;
        #pragma unroll
        for (int i = 0; i < 4; ++i) r[i] = (a[i] * f0 + bb[i] * f1) * inv;
        *(f32x4*)(dst + row * 64 + c) = r;
    }
}

// ---------------------------------------------------------------------------
extern "C" void kernel_launch(void* const* d_in, const int* in_sizes, int n_in,
                              void* d_out, int out_size, void* d_ws, size_t ws_size,
                              hipStream_t stream) {
    const float* x  = (const float*)d_in[0];
    const float* Wq = (const float*)d_in[1];
    const float* Wk = (const float*)d_in[2];
    const float* Wv = (const float*)d_in[3];
    float* out = (float*)d_out;

    char* ws = (char*)d_ws;
    short* Q     = (short*)(ws);
    short* K     = (short*)(ws + (size_t)2 * 1024 * 1024);
    short* Vt    = (short*)(ws + (size_t)4 * 1024 * 1024);
    short* Wt    = (short*)(ws + (size_t)6 * 1024 * 1024);
    float* Opart = (float*)(ws + (size_t)8 * 1024 * 1024);   // 512*16KB = 8MB
    float* Mlp   = (float*)(ws + (size_t)16 * 1024 * 1024);  // 512*512B = 256KB

    wt_kernel<<<dim3(16, 3), 256, 0, stream>>>(Wq, Wk, Wv, Wt);
    qkv_kernel<<<BT / 32, 256, 0, stream>>>(x, Wt, Q, K, Vt);
    attn_kernel<<<dim3(BATCH, TLEN / 32), 256, 0, stream>>>(Q, K, Vt, Opart, Mlp);
    attn_merge<<<dim3(BATCH, TLEN / 64), 256, 0, stream>>>(Opart, Mlp, out);
}